// Round 1
// baseline (1303.356 us; speedup 1.0000x reference)
//
#include <hip/hip_runtime.h>
#include <hip/hip_cooperative_groups.h>
#include <math.h>

namespace cg = cooperative_groups;

#define Bq 4
#define Nq 512
#define Dq 128

// hyperparameters
#define C_UNTANH   3.0f
#define C_BSCALE   1.8477590650225735f   // sqrt(2+sqrt(2))
#define C_INVSQRTD 0.08838834764831845f  // 1/sqrt(128)
#define C_WD       1e-4f
#define C_MOM      0.9f
#define C_LR       0.01f
#define C_WSCALE   4.0f
#define C_SPARSE   0.0009765625f         // 0.5/N

// ---------------- forward: pred/key/query = buntanh(state @ W_i), float4 loads ----------------
__global__ __launch_bounds__(256) void k_fwd(const float* __restrict__ state,
    const float* __restrict__ w1, const float* __restrict__ w2, const float* __restrict__ w3,
    float* __restrict__ pred, float* __restrict__ keyv, float* __restrict__ qry) {
  int bn = blockIdx.x;
  int t = threadIdx.x;
  int g = t & 31;   // float4 column group (cols 4g..4g+3)
  int h = t >> 5;   // row chunk 0..7 (rows 16h..16h+15)
  __shared__ float xs[Dq];
  __shared__ float4 red[8][32];
  if (t < Dq) xs[t] = state[bn * Dq + t];
  __syncthreads();
  const float* Ws[3] = {w1, w2, w3};
  float* dsts[3] = {pred, keyv, qry};  // w1->prediction, w2->keys, w3->queries
  for (int p = 0; p < 3; p++) {
    const float4* W4 = (const float4*)(Ws[p] + (size_t)bn * Dq * Dq);
    float4 acc = {0.f, 0.f, 0.f, 0.f};
#pragma unroll
    for (int i = 0; i < 16; i++) {
      int j = h * 16 + i;
      float x = xs[j];
      float4 w = W4[j * 32 + g];
      acc.x += x * w.x; acc.y += x * w.y; acc.z += x * w.z; acc.w += x * w.w;
    }
    red[h][g] = acc;
    __syncthreads();
    if (t < Dq) {
      const float* rp = (const float*)&red[0][0];
      float ssum = 0.f;
#pragma unroll
      for (int h2 = 0; h2 < 8; h2++) ssum += rp[h2 * 128 + t];
      float r = C_UNTANH * tanhf(ssum / C_UNTANH) * C_BSCALE;
      dsts[p][bn * Dq + t] = r;
    }
    __syncthreads();
  }
}

// ---------------- raw_S = Q K^T / sqrt(D), with per-b sum of squares ----------------
__global__ __launch_bounds__(256) void k_qk(const float* __restrict__ qry,
    const float* __restrict__ keyv, float* __restrict__ rawS, double* __restrict__ part) {
  __shared__ float Qs[16][132];   // 132: keeps rows 16B-aligned for float4 reads
  __shared__ float Ks[16][132];
  __shared__ double red[256];
  int b = blockIdx.z, n0 = blockIdx.x * 16, m0 = blockIdx.y * 16;
  int t = threadIdx.x;
#pragma unroll
  for (int i = 0; i < 8; i++) {
    int idx = i * 256 + t;
    int r = idx >> 7, c = idx & 127;
    Qs[r][c] = qry[((size_t)b * Nq + n0 + r) * Dq + c];
    Ks[r][c] = keyv[((size_t)b * Nq + m0 + r) * Dq + c];
  }
  __syncthreads();
  int tn = t >> 4, tm = t & 15;
  const float4* Q4 = (const float4*)&Qs[tn][0];
  const float4* K4 = (const float4*)&Ks[tm][0];
  float a = 0.f;
#pragma unroll
  for (int d = 0; d < 32; d++) {
    float4 q = Q4[d];
    float4 k = K4[d];
    a += q.x * k.x + q.y * k.y + q.z * k.z + q.w * k.w;
  }
  a *= C_INVSQRTD;
  rawS[((size_t)b * Nq + n0 + tn) * Nq + m0 + tm] = a;
  red[t] = (double)a * (double)a;
  __syncthreads();
  for (int s = 128; s > 0; s >>= 1) { if (t < s) red[t] += red[t + s]; __syncthreads(); }
  if (t == 0) part[(size_t)b * 1024 + blockIdx.y * 32 + blockIdx.x] = red[0];
}

// ---------------- cooperative A-pipeline: acc + ema + sinkhorn x5 + sparse + sinkhorn x5 ----------------
// grid = 64 blocks (16 stripes of 32 cols per b), 256 threads.
// Each thread owns rows r = rq+32k (k=0..15), cols 4*c4..4*c4+3 of its stripe, in registers.
__global__ __launch_bounds__(256) void k_Apipe(float* __restrict__ A,
    const float* __restrict__ A_ema, const double* __restrict__ part,
    const int* __restrict__ stepc, float* __restrict__ outA, float* __restrict__ prs) {
  cg::grid_group grid = cg::this_grid();
  int blk = blockIdx.x;
  int b = blk >> 4;
  int s = blk & 15;
  int m0 = s * 32;
  int t = threadIdx.x;
  int c4 = t & 7;
  int rq = t >> 3;
  __shared__ float rs_l[512];
  __shared__ float cs_l[32];
  __shared__ float4 carr[32][8];
  __shared__ double dred[256];

  // per-b sum of squares (redundant per block, no sync needed between blocks)
  double ps = 0.0;
  for (int i = t; i < 1024; i += 256) ps += part[(size_t)b * 1024 + i];
  dred[t] = ps;
  __syncthreads();
  for (int k = 128; k > 0; k >>= 1) { if (t < k) dred[t] += dred[t + k]; __syncthreads(); }
  float invs = rsqrtf((float)(dred[0] / (double)(Nq * Nq)) + 1e-8f);
  int step1 = (stepc[0] == 1);

  const size_t brow = (size_t)b * Nq;
  float4 vS[16];

  // EMA + o_A write + initial per-stripe row partial sums
#pragma unroll
  for (int k = 0; k < 16; k++) {
    int r = rq + 32 * k;
    const float4* Ar = (const float4*)(A + (brow + r) * Nq + m0);
    float4 v = Ar[c4];
    v.x *= invs; v.y *= invs; v.z *= invs; v.w *= invs;
    if (!step1) {
      const float4* Er = (const float4*)(A_ema + (brow + r) * Nq + m0);
      float4 e = Er[c4];
      v.x = 0.9f * e.x + 0.1f * v.x;
      v.y = 0.9f * e.y + 0.1f * v.y;
      v.z = 0.9f * e.z + 0.1f * v.z;
      v.w = 0.9f * e.w + 0.1f * v.w;
    }
    vS[k] = v;
    float4* Or = (float4*)(outA + (brow + r) * Nq + m0);
    Or[c4] = v;
    float p = v.x + v.y + v.z + v.w;
    p += __shfl_xor(p, 1);
    p += __shfl_xor(p, 2);
    p += __shfl_xor(p, 4);
    if (c4 == 0) prs[((size_t)(b * 16 + s)) * 512 + r] = p;
  }
  __threadfence();
  grid.sync();

  for (int iter = 0; iter < 10; iter++) {
    // gather full row sums (all 16 stripes) -> reciprocal
    for (int r = t; r < 512; r += 256) {
      float ssum = 0.f;
#pragma unroll
      for (int s2 = 0; s2 < 16; s2++) ssum += prs[((size_t)(b * 16 + s2)) * 512 + r];
      rs_l[r] = 1.0f / (ssum + 1e-6f);
    }
    __syncthreads();
    // row divide + column partials (block-local)
    float4 cacc = {0.f, 0.f, 0.f, 0.f};
#pragma unroll
    for (int k = 0; k < 16; k++) {
      int r = rq + 32 * k;
      float rv = rs_l[r];
      float4 v = vS[k];
      v.x *= rv; v.y *= rv; v.z *= rv; v.w *= rv;
      vS[k] = v;
      cacc.x += v.x; cacc.y += v.y; cacc.z += v.z; cacc.w += v.w;
    }
    carr[rq][c4] = cacc;
    __syncthreads();
    if (t < 32) {
      const float* cf = (const float*)&carr[0][0];
      float ssum = 0.f;
#pragma unroll
      for (int q = 0; q < 32; q++) ssum += cf[q * 32 + t];
      cs_l[t] = 1.0f / (ssum + 1e-6f);
    }
    __syncthreads();
    float4 cm = ((const float4*)cs_l)[c4];
    int last = (iter == 9);
    // col divide (+ sparsify after sinkhorn #1) + next row partials or final write
#pragma unroll
    for (int k = 0; k < 16; k++) {
      int r = rq + 32 * k;
      float4 v = vS[k];
      v.x *= cm.x; v.y *= cm.y; v.z *= cm.z; v.w *= cm.w;
      if (iter == 4) {
        v.x = (v.x > C_SPARSE) ? v.x : 0.f;
        v.y = (v.y > C_SPARSE) ? v.y : 0.f;
        v.z = (v.z > C_SPARSE) ? v.z : 0.f;
        v.w = (v.w > C_SPARSE) ? v.w : 0.f;
      }
      vS[k] = v;
      if (!last) {
        float p = v.x + v.y + v.z + v.w;
        p += __shfl_xor(p, 1);
        p += __shfl_xor(p, 2);
        p += __shfl_xor(p, 4);
        if (c4 == 0) prs[((size_t)(b * 16 + s)) * 512 + r] = p;
      } else {
        float4* Ar = (float4*)(A + (brow + r) * Nq + m0);
        Ar[c4] = v;
      }
    }
    if (!last) {
      __threadfence();
      grid.sync();
      __syncthreads();
    }
  }
}

// ---------------- target = A @ output ; rows 0,1 = env (LDS-tiled, 4 rows/block) ----------------
__global__ __launch_bounds__(256) void k_target(const float* __restrict__ A,
    const float* __restrict__ output, const float* __restrict__ eye_env,
    const float* __restrict__ stomach_env, float* __restrict__ out_state) {
  int blk = blockIdx.x;
  int b = blk >> 7;
  int n0 = (blk & 127) * 4;
  int t = threadIdx.x;
  int tr = t >> 7;     // 0,1
  int c = t & 127;
  __shared__ float as[4][Nq];        // 8 KB
  __shared__ float tile[64][Dq];     // 32 KB
  const float4* Ab4 = (const float4*)(A + ((size_t)b * Nq + n0) * Nq);
  float4* as4 = (float4*)&as[0][0];
  as4[t] = Ab4[t];
  as4[t + 256] = Ab4[t + 256];
  float acc0 = 0.f, acc1 = 0.f;
  const float4* ob4 = (const float4*)(output + (size_t)b * Nq * Dq);
  for (int m0 = 0; m0 < Nq; m0 += 64) {
    __syncthreads();
    float4* t4 = (float4*)&tile[0][0];
    const float4* src = ob4 + m0 * 32;
#pragma unroll
    for (int i = 0; i < 8; i++) t4[i * 256 + t] = src[i * 256 + t];
    __syncthreads();
#pragma unroll 8
    for (int m = 0; m < 64; m++) {
      float ov = tile[m][c];
      acc0 += as[tr][m0 + m] * ov;
      acc1 += as[tr + 2][m0 + m] * ov;
    }
  }
  int na = n0 + tr;
  int nb = na + 2;  // always >= 2
  float v0 = acc0;
  if (na == 0) v0 = eye_env[b * Dq + c];
  if (na == 1) v0 = stomach_env[b * Dq + c];
  out_state[((size_t)b * Nq + na) * Dq + c] = v0;
  out_state[((size_t)b * Nq + nb) * Dq + c] = acc1;
}

// ---------------- error signals + softmax/plasticity + mean(state^2) ----------------
__device__ __forceinline__ void softmax_plast(float e, const float* __restrict__ eb,
    float* __restrict__ pl, int base, int t, float* red) {
  red[t] = e;
  __syncthreads();
  for (int s = 64; s > 0; s >>= 1) { if (t < s) red[t] = fmaxf(red[t], red[t + s]); __syncthreads(); }
  float mx = red[0];
  __syncthreads();
  float ex = expf(e - mx);
  red[t] = ex;
  __syncthreads();
  for (int s = 64; s > 0; s >>= 1) { if (t < s) red[t] += red[t + s]; __syncthreads(); }
  float Ec = ex / red[0];
  __syncthreads();
  float En = eb[base] * 0.99f + 0.01f * Ec;  // EMA_SPEED = 0.01
  float adv = Ec - En;
  float x = adv * 4.0f;                      // REW_SENS
  pl[base] = 1.0f + x / sqrtf(x * x + 1e-8f);
}

__global__ __launch_bounds__(128) void k_err(const float* __restrict__ pred,
    const float* __restrict__ qry, const float* __restrict__ keyv,
    const float* __restrict__ target, const float* __restrict__ state,
    const float* __restrict__ eb1, const float* __restrict__ eb2, const float* __restrict__ eb3,
    float* __restrict__ err1, float* __restrict__ err2, float* __restrict__ err3,
    float* __restrict__ pl1, float* __restrict__ pl2, float* __restrict__ pl3,
    float* __restrict__ msn) {
  int bn = blockIdx.x, t = threadIdx.x;
  int base = bn * Dq + t;
  float pr = pred[base], qv = qry[base], kv = keyv[base], tg = target[base];
  float e1b = pr - tg;
  float e2 = kv - e1b;
  float e3 = qv - e2;
  float e1 = pr - (tg + e3);
  err1[base] = e1; err2[base] = e2; err3[base] = e3;
  __shared__ float red[128];
  float st = state[base];
  red[t] = st * st;
  __syncthreads();
  for (int s = 64; s > 0; s >>= 1) { if (t < s) red[t] += red[t + s]; __syncthreads(); }
  if (t == 0) msn[bn] = red[0] / (float)Dq;
  __syncthreads();
  softmax_plast(e1, eb1, pl1, base, t, red);
  softmax_plast(e2, eb2, pl2, base, t, red);
  softmax_plast(e3, eb3, pl3, base, t, red);
}

// ---------------- fused weight update for all 3 pieces, Wn in registers ----------------
__device__ __forceinline__ float stepw(float w, float g, float c, float st, float mk, double* ssq) {
  float grad = (c * st - C_WD * w) * mk;     // (plast*lg1 - WD*W)*mask
  float gn = C_MOM * g + (1.0f - C_MOM) * grad;
  float wn = w + C_LR * gn;
  *ssq += (double)wn * (double)wn;
  return wn;
}

__global__ __launch_bounds__(256) void k_step3(
    const float* __restrict__ w1, const float* __restrict__ w2, const float* __restrict__ w3,
    const float* __restrict__ g1, const float* __restrict__ g2, const float* __restrict__ g3,
    const float* __restrict__ err1, const float* __restrict__ err2, const float* __restrict__ err3,
    const float* __restrict__ pl1, const float* __restrict__ pl2, const float* __restrict__ pl3,
    const float* __restrict__ state, const float* __restrict__ msn, const int* __restrict__ stepc,
    float* __restrict__ ow1, float* __restrict__ ow2, float* __restrict__ ow3) {
  int p = blockIdx.x >> 11;
  int bn = blockIdx.x & 2047;
  const float* W   = (p == 0) ? w1 : (p == 1) ? w2 : w3;
  const float* G   = (p == 0) ? g1 : (p == 1) ? g2 : g3;
  const float* err = (p == 0) ? err1 : (p == 1) ? err2 : err3;
  const float* pl  = (p == 0) ? pl1 : (p == 1) ? pl2 : pl3;
  float* outW      = (p == 0) ? ow1 : (p == 1) ? ow2 : ow3;
  int t = threadIdx.x;
  __shared__ __align__(16) float ers[Dq];
  __shared__ __align__(16) float pls[Dq];
  __shared__ __align__(16) float sts[Dq];
  __shared__ __align__(16) float msk[Dq];
  __shared__ double red[256];
  if (t < Dq) {
    ers[t] = err[bn * Dq + t];
    pls[t] = pl[bn * Dq + t];
    sts[t] = state[bn * Dq + t];
    float center = fmodf((float)stepc[0], 128.0f);  // (step*SPEED) % D
    float d = fabsf((float)t - center);
    d = fminf(d, 128.0f - d);
    msk[t] = expf(-(d * d) * (1.0f / 32.0f));  // 2*WIDTH^2 = 32
  }
  float msnv = msn[bn];
  __syncthreads();
  const float4* W4 = (const float4*)(W + (size_t)bn * Dq * Dq);
  const float4* G4 = (const float4*)(G + (size_t)bn * Dq * Dq);
  float4 wn[16];
  double ssq = 0.0;
#pragma unroll
  for (int i = 0; i < 16; i++) {
    int f4 = i * 256 + t;
    int row = f4 >> 5;
    float4 w4v = W4[f4];
    float4 g4v = G4[f4];
    float4 st4 = ((const float4*)sts)[f4 & 31];
    float4 mk4 = ((const float4*)msk)[f4 & 31];
    float ep = ers[row];
    float denom = sqrtf(ep * ep * msnv + 1e-8f);
    float c = -pls[row] * ep / denom;  // lg1 = -ep*st_q/denom ; grad_in = plast*lg1
    float4 o;
    o.x = stepw(w4v.x, g4v.x, c, st4.x, mk4.x, &ssq);
    o.y = stepw(w4v.y, g4v.y, c, st4.y, mk4.y, &ssq);
    o.z = stepw(w4v.z, g4v.z, c, st4.z, mk4.z, &ssq);
    o.w = stepw(w4v.w, g4v.w, c, st4.w, mk4.w, &ssq);
    wn[i] = o;
  }
  red[t] = ssq;
  __syncthreads();
  for (int k = 128; k > 0; k >>= 1) { if (t < k) red[t] += red[t + k]; __syncthreads(); }
  float mean = (float)(red[0] / (double)(Dq * Dq));
  float scale = C_WSCALE / sqrtf(mean + 1e-8f);
  float4* out4 = (float4*)(outW + (size_t)bn * Dq * Dq);
#pragma unroll
  for (int i = 0; i < 16; i++) {
    int f4 = i * 256 + t;
    float4 v = wn[i];
    v.x *= scale; v.y *= scale; v.z *= scale; v.w *= scale;
    out4[f4] = v;
  }
}

extern "C" void kernel_launch(void* const* d_in, const int* in_sizes, int n_in,
                              void* d_out, int out_size, void* d_ws, size_t ws_size,
                              hipStream_t stream) {
  const float* state   = (const float*)d_in[0];
  const float* output  = (const float*)d_in[1];
  const float* A_ema   = (const float*)d_in[2];
  const float* w1      = (const float*)d_in[3];
  const float* w2      = (const float*)d_in[4];
  const float* w3      = (const float*)d_in[5];
  const float* g1      = (const float*)d_in[6];
  const float* g2      = (const float*)d_in[7];
  const float* g3      = (const float*)d_in[8];
  const float* eb1     = (const float*)d_in[9];
  const float* eb2     = (const float*)d_in[10];
  const float* eb3     = (const float*)d_in[11];
  const float* eye     = (const float*)d_in[12];
  const float* stomach = (const float*)d_in[13];
  const int*   stepc   = (const int*)d_in[14];

  float* out = (float*)d_out;
  float* o_state = out;                    // [B,N,D] 262144
  float* o_out   = out + 262144;           // prediction
  float* o_w1    = out + 524288;           // [B,N,D,D] 33554432
  float* o_w2    = o_w1 + 33554432;
  float* o_w3    = o_w2 + 33554432;
  float* o_A     = o_w3 + 33554432;        // [B,N,N] 1048576

  float* ws = (float*)d_ws;
  float* A    = ws;                 // 1048576 (rawS, then final sinkhorn A)
  float* qry  = ws + 1048576;       // 262144
  float* keyv = ws + 1310720;       // 262144
  float* err1 = ws + 1572864;
  float* err2 = ws + 1835008;
  float* err3 = ws + 2097152;
  float* pl1  = ws + 2359296;
  float* pl2  = ws + 2621440;
  float* pl3  = ws + 2883584;
  float* msn  = ws + 3145728;       // 2048
  double* part = (double*)(ws + 3147776);  // 4096 doubles
  float* prs  = err1;  // 32768-float scratch; free until k_err runs (after k_Apipe)

  // forward (pred written straight into new_output region)
  k_fwd<<<Bq * Nq, 256, 0, stream>>>(state, w1, w2, w3, o_out, keyv, qry);
  // attention raw scores + per-b sumsq partials
  k_qk<<<dim3(32, 32, Bq), 256, 0, stream>>>(qry, keyv, A, part);
  // fused: acc reduce + rms/ema (writes o_A) + sinkhorn x5 + sparsify + sinkhorn x5
  {
    float* A_ = A;
    const float* Aema_ = A_ema;
    const double* part_ = part;
    const int* stepc_ = stepc;
    float* oA_ = o_A;
    float* prs_ = prs;
    void* args[] = {&A_, &Aema_, &part_, &stepc_, &oA_, &prs_};
    hipLaunchCooperativeKernel((void*)k_Apipe, dim3(Bq * 16), dim3(256), args, 0, stream);
  }
  // target (rows 0,1 = env)
  k_target<<<Bq * 128, 256, 0, stream>>>(A, output, eye, stomach, o_state);
  // errors, softmax plasticity, mean(state^2)
  k_err<<<Bq * Nq, 128, 0, stream>>>(o_out, qry, keyv, o_state, state,
                                     eb1, eb2, eb3, err1, err2, err3, pl1, pl2, pl3, msn);
  // fused weight updates (all 3 pieces)
  k_step3<<<3 * Bq * Nq, 256, 0, stream>>>(w1, w2, w3, g1, g2, g3,
                                           err1, err2, err3, pl1, pl2, pl3,
                                           state, msn, stepc, o_w1, o_w2, o_w3);
}